// Round 13
// baseline (32.315 us; speedup 1.0000x reference)
//
#include <hip/hip_runtime.h>

// Problem constants (fixed by reference setup_inputs)
#define NB 4
#define NC 64
#define NH 256
#define NW 256
#define HW (NH * NW)          // 65536 floats per (b,c) plane
#define RPB 4                 // output rows per block
#define CSTEP 4               // channels staged per step
#define NSTEP (NC / CSTEP)    // 16 steps

// Evidence: per-CU miss-concurrency caps byte throughput (~50GB/s/CU): R4=R10=R12
// at 30-34us, VALUBusy<=21%. R11 cut logical bytes 256->160MB via LDS staging but
// its per-step __syncthreads drained vmcnt(0) -> un-overlapped stages, 32us.
// R13 = R11 staging (correctness-verified) + T3/T4 pipeline: counted
// s_waitcnt vmcnt(5) + raw s_barrier, stage(s+1) loads stay in flight across
// barriers. No full drain inside the loop.
__device__ __forceinline__ void gload_lds16(const float* g, float* l) {
    __builtin_amdgcn_global_load_lds(
        (const __attribute__((address_space(1))) void*)g,
        (__attribute__((address_space(3))) void*)l, 16, 0, 0);
}

__global__ __launch_bounds__(512) void k_fused(
    const float* __restrict__ img, const float* __restrict__ ev,
    float* __restrict__ out)
{
    __shared__ float lds[2][CSTEP][10][NW];   // 80 KB: rows 0..5 img (h0-1..h0+4), 6..9 ev (h0..h0+3)
    __shared__ float redbuf[RPB][48][64];     // 48 KB: 2-way channel reduction; total 128 KB

    const int lane = threadIdx.x & 63;
    const int wv   = threadIdx.x >> 6;        // 0..7
    const int row  = wv >> 1;                 // 0..3: output row within tile
    const int g    = wv & 1;                  // channel half within a step

    // XCD swizzle: 256 blocks, 8 XCDs; consecutive h-tiles share halo rows in L2.
    const int bid = blockIdx.x;
    const int swz = (bid & 7) * 32 + (bid >> 3);   // bijective, 256 % 8 == 0
    const int b   = swz >> 6;
    const int h0  = (swz & 63) << 2;
    const int h   = h0 + row;
    const int w   = lane << 2;

    const float hmf = (h > 0) ? 1.f : 0.f;         // zero-mask row h-1
    const float hpf = (h < NH - 1) ? 1.f : 0.f;    // zero-mask row h+1

    const size_t ibb = (size_t)b * NC * HW;
    const float* gimg = img + ibb;
    const float* gev  = ev + ibb;

    float acc[8][4], si[3][4], se[4];
#pragma unroll
    for (int k = 0; k < 8; ++k)
#pragma unroll
        for (int x = 0; x < 4; ++x) acc[k][x] = 0.f;
#pragma unroll
    for (int r = 0; r < 3; ++r)
#pragma unroll
        for (int x = 0; x < 4; ++x) si[r][x] = 0.f;
#pragma unroll
    for (int x = 0; x < 4; ++x) se[x] = 0.f;

    // Stage step snext into buffer snext&1: 40 row-loads (4ch x 10 rows),
    // exactly 5 per wave (vmcnt counting relies on this), each 1 KB linear.
#define STAGE(snext)                                                         \
    {                                                                        \
        const int bufi_ = (snext) & 1;                                       \
        _Pragma("unroll")                                                    \
        for (int j = 0; j < 5; ++j) {                                        \
            const int t  = wv * 5 + j;                                       \
            const int cc = t / 10;                                           \
            const int r  = t - cc * 10;                                      \
            const int c  = (snext) * CSTEP + cc;                             \
            const float* src;                                                \
            if (r < 6) {                                                     \
                int sr = h0 - 1 + r;                                         \
                sr = sr < 0 ? 0 : (sr > NH - 1 ? NH - 1 : sr);               \
                src = gimg + (size_t)c * HW + (size_t)sr * NW;               \
            } else {                                                         \
                src = gev + (size_t)c * HW + (size_t)(h0 + r - 6) * NW;      \
            }                                                                \
            gload_lds16(src + lane * 4, &lds[bufi_][cc][r][0]);              \
        }                                                                    \
    }

    // Compute one channel from LDS (verified in R11's passing run).
#define COMPUTECH(bufi, cc)                                                  \
    {                                                                        \
        const float4* Mp = (const float4*)&lds[bufi][cc][row + 0][0];        \
        const float4* Zp = (const float4*)&lds[bufi][cc][row + 1][0];        \
        const float4* Pp = (const float4*)&lds[bufi][cc][row + 2][0];        \
        const float4* Ep = (const float4*)&lds[bufi][cc][6 + row][0];        \
        float4 M = Mp[lane], Z = Zp[lane], P = Pp[lane], E = Ep[lane];       \
        M.x *= hmf; M.y *= hmf; M.z *= hmf; M.w *= hmf;                      \
        P.x *= hpf; P.y *= hpf; P.z *= hpf; P.w *= hpf;                      \
        float lm = __shfl_up(M.w, 1);                                        \
        float lz = __shfl_up(Z.w, 1);                                        \
        float lp = __shfl_up(P.w, 1);                                        \
        float rm = __shfl_down(M.x, 1);                                      \
        float rz = __shfl_down(Z.x, 1);                                      \
        float rp = __shfl_down(P.x, 1);                                      \
        if (lane == 0)  { lm = 0.f; lz = 0.f; lp = 0.f; }                    \
        if (lane == 63) { rm = 0.f; rz = 0.f; rp = 0.f; }                    \
        float m6[6] = { lm, M.x, M.y, M.z, M.w, rm };                        \
        float z6[6] = { lz, Z.x, Z.y, Z.z, Z.w, rz };                        \
        float p6[6] = { lp, P.x, P.y, P.z, P.w, rp };                        \
        float sqm[6], sqz[6], sqp[6];                                        \
        for (int i = 0; i < 6; ++i) {                                        \
            sqm[i] = m6[i] * m6[i];                                          \
            sqz[i] = z6[i] * z6[i];                                          \
            sqp[i] = p6[i] * p6[i];                                          \
        }                                                                    \
        for (int x = 0; x < 4; ++x) {                                        \
            si[0][x] += sqm[x + 1];                                          \
            si[1][x] += sqz[x + 1];                                          \
            si[2][x] += sqp[x + 1];                                          \
        }                                                                    \
        se[0] = fmaf(E.x, E.x, se[0]);                                       \
        se[1] = fmaf(E.y, E.y, se[1]);                                       \
        se[2] = fmaf(E.z, E.z, se[2]);                                       \
        se[3] = fmaf(E.w, E.w, se[3]);                                       \
        float pe[4] = { z6[1] * E.x, z6[2] * E.y, z6[3] * E.z, z6[4] * E.w };\
        for (int x = 0; x < 4; ++x) {                                        \
            acc[0][x] = fmaf(sqm[x],     pe[x], acc[0][x]);                  \
            acc[1][x] = fmaf(sqm[x + 1], pe[x], acc[1][x]);                  \
            acc[2][x] = fmaf(sqm[x + 2], pe[x], acc[2][x]);                  \
            acc[3][x] = fmaf(sqz[x],     pe[x], acc[3][x]);                  \
            acc[4][x] = fmaf(sqz[x + 2], pe[x], acc[4][x]);                  \
            acc[5][x] = fmaf(sqp[x],     pe[x], acc[5][x]);                  \
            acc[6][x] = fmaf(sqp[x + 1], pe[x], acc[6][x]);                  \
            acc[7][x] = fmaf(sqp[x + 2], pe[x], acc[7][x]);                  \
        }                                                                    \
    }

    STAGE(0);
    for (int s = 0; s < NSTEP; ++s) {
        if (s + 1 < NSTEP) {
            STAGE(s + 1);                                  // 5 more loads in flight
            asm volatile("s_waitcnt vmcnt(5)" ::: "memory");  // stage(s) landed
        } else {
            asm volatile("s_waitcnt vmcnt(0)" ::: "memory");  // last: drain stage(s)
        }
        __builtin_amdgcn_sched_barrier(0);
        __builtin_amdgcn_s_barrier();                      // buf[s&1] visible to all
        asm volatile("" ::: "memory");
        {
            const int bufi = s & 1;
            const int c0 = g * 2;
            COMPUTECH(bufi, c0);
            COMPUTECH(bufi, c0 + 1);
        }
        asm volatile("" ::: "memory");
        __builtin_amdgcn_sched_barrier(0);
        __builtin_amdgcn_s_barrier();                      // done reading before next overwrite
    }
#undef STAGE
#undef COMPUTECH

    __syncthreads();   // epilogue boundary (outside hot loop; full drain OK)

    // ---- 2-way channel-half reduction via redbuf ----
    if (g == 1) {
#pragma unroll
        for (int k = 0; k < 8; ++k)
#pragma unroll
            for (int x = 0; x < 4; ++x) redbuf[row][k * 4 + x][lane] = acc[k][x];
#pragma unroll
        for (int r = 0; r < 3; ++r)
#pragma unroll
            for (int x = 0; x < 4; ++x) redbuf[row][32 + r * 4 + x][lane] = si[r][x];
#pragma unroll
        for (int x = 0; x < 4; ++x) redbuf[row][44 + x][lane] = se[x];
    }
    __syncthreads();
    if (g == 1) return;
#pragma unroll
    for (int k = 0; k < 8; ++k)
#pragma unroll
        for (int x = 0; x < 4; ++x) acc[k][x] += redbuf[row][k * 4 + x][lane];
#pragma unroll
    for (int r = 0; r < 3; ++r)
#pragma unroll
        for (int x = 0; x < 4; ++x) si[r][x] += redbuf[row][32 + r * 4 + x][lane];
#pragma unroll
    for (int x = 0; x < 4; ++x) se[x] += redbuf[row][44 + x][lane];

    // ---- epilogue (one wave per row): reciprocal norms, windows, relu ----
    float rnm[4], rnz[4], rnp[4], rne[4];
#pragma unroll
    for (int x = 0; x < 4; ++x) {
        rnm[x] = 1.f / fmaxf(sqrtf(si[0][x]), 1e-12f);
        rnz[x] = 1.f / fmaxf(sqrtf(si[1][x]), 1e-12f);
        rnp[x] = 1.f / fmaxf(sqrtf(si[2][x]), 1e-12f);
        rne[x] = 1.f / fmaxf(sqrtf(se[x]), 1e-12f);
    }

    float lnm = __shfl_up(rnm[3], 1);
    float lnz = __shfl_up(rnz[3], 1);
    float lnp = __shfl_up(rnp[3], 1);
    float rnm_ = __shfl_down(rnm[0], 1);
    float rnz_ = __shfl_down(rnz[0], 1);
    float rnp_ = __shfl_down(rnp[0], 1);
    if (lane == 0)  { lnm = 0.f; lnz = 0.f; lnp = 0.f; }
    if (lane == 63) { rnm_ = 0.f; rnz_ = 0.f; rnp_ = 0.f; }

    float nm6[6] = { lnm, rnm[0], rnm[1], rnm[2], rnm[3], rnm_ };
    float nz6[6] = { lnz, rnz[0], rnz[1], rnz[2], rnz[3], rnz_ };
    float np6[6] = { lnp, rnp[0], rnp[1], rnp[2], rnp[3], rnp_ };

    float ctr[4];
#pragma unroll
    for (int x = 0; x < 4; ++x) ctr[x] = nz6[x + 1] * rne[x];

    float* outp = out + (((size_t)b * 8) * NH + h) * NW + w;
#pragma unroll
    for (int k = 0; k < 8; ++k) {
        float nbv[4];
#pragma unroll
        for (int x = 0; x < 4; ++x) {
            float v;
            switch (k) {
                case 0: v = nm6[x];     break;
                case 1: v = nm6[x + 1]; break;
                case 2: v = nm6[x + 2]; break;
                case 3: v = nz6[x];     break;
                case 4: v = nz6[x + 2]; break;
                case 5: v = np6[x];     break;
                case 6: v = np6[x + 1]; break;
                default: v = np6[x + 2]; break;
            }
            nbv[x] = v;
        }
        float4 o;
        o.x = fmaxf(acc[k][0] * (nbv[0] * nbv[0]) * ctr[0], 0.f);
        o.y = fmaxf(acc[k][1] * (nbv[1] * nbv[1]) * ctr[1], 0.f);
        o.z = fmaxf(acc[k][2] * (nbv[2] * nbv[2]) * ctr[2], 0.f);
        o.w = fmaxf(acc[k][3] * (nbv[3] * nbv[3]) * ctr[3], 0.f);
        *(float4*)(outp + (size_t)k * NH * NW) = o;
    }
}

extern "C" void kernel_launch(void* const* d_in, const int* in_sizes, int n_in,
                              void* d_out, int out_size, void* d_ws, size_t ws_size,
                              hipStream_t stream) {
    (void)in_sizes; (void)n_in; (void)out_size; (void)d_ws; (void)ws_size;
    const float* img = (const float*)d_in[0];
    const float* ev  = (const float*)d_in[1];
    float* out = (float*)d_out;

    // 256 blocks (4 batches x 64 h-tiles of 4 rows), 512 threads (8 waves)
    k_fused<<<NB * (NH / RPB), 512, 0, stream>>>(img, ev, out);
}

// Round 14
// 29.028 us; speedup vs baseline: 1.1133x; 1.1133x over previous
//
#include <hip/hip_runtime.h>

// Problem constants (fixed by reference setup_inputs)
#define NB 4
#define NC 64
#define NH 256
#define NW 256
#define HW (NH * NW)            // 65536 floats per (b,c) plane
#define CPW 16                  // channels per wave (NC / 4 waves)

__device__ __forceinline__ float4 f4zero() { return make_float4(0.f, 0.f, 0.f, 0.f); }

// BEST VARIANT (R4, 30.4us): fused one-pass kernel. One block = one image row
// (b,h). 4 waves; wave wv handles channels [wv*16, wv*16+16). Lane owns 4
// consecutive w (float4); horizontal neighbors via wave shuffles.
//
// Roofline evidence (R4..R13): per-CU in-flight byte capacity K~7KB caps
// throughput at K/latency ~ 14B/cy/CU (mixed L2/L3). All structural variants
// (2x waves R10, deep MLP R9, LDS staging R11, counted-vmcnt pipeline R13,
// L1 tiling R12) land 30-34us; byte reduction trades exactly against latency
// increase. This kernel sits within ~10% of that roofline.
__global__ __launch_bounds__(256) void k_fused(
    const float* __restrict__ img, const float* __restrict__ ev,
    float* __restrict__ out)
{
    __shared__ float red[2][48][64];   // two reduction slots, [value][lane]

    const int lane = threadIdx.x & 63;
    const int wv   = threadIdx.x >> 6;           // 0..3 = channel chunk

    // XCD-aware swizzle: 1024 blocks, 8 XCDs -> contiguous 128-row chunks per
    // XCD so h-adjacent rows (which share img rows) live on the same L2.
    const int bid = blockIdx.x;
    const int swz = (bid & 7) * 128 + (bid >> 3);   // bijective, 1024 % 8 == 0
    const int b = swz >> 8;
    const int h = swz & 255;
    const int w = lane << 2;

    const bool hm = (h > 0);
    const bool hp = (h < NH - 1);

    const size_t base = (size_t)b * NC * HW + (size_t)(wv * CPW) * HW
                      + (size_t)h * NW + w;
    const float* ibase = img + base;
    const float* ebase = ev + base;

    float acc[8][4];
    float si[3][4];
    float se[4];
#pragma unroll
    for (int k = 0; k < 8; ++k)
#pragma unroll
        for (int x = 0; x < 4; ++x) acc[k][x] = 0.f;
#pragma unroll
    for (int r = 0; r < 3; ++r)
#pragma unroll
        for (int x = 0; x < 4; ++x) si[r][x] = 0.f;
#pragma unroll
    for (int x = 0; x < 4; ++x) se[x] = 0.f;

#pragma unroll 2
    for (int c = 0; c < CPW; ++c) {
        const float* p = ibase + (size_t)c * HW;
        float4 zm = hm ? *(const float4*)(p - NW) : f4zero();
        float4 zz = *(const float4*)(p);
        float4 zp = hp ? *(const float4*)(p + NW) : f4zero();
        float4 ee = *(const float4*)(ebase + (size_t)c * HW);

        float lm = __shfl_up(zm.w, 1);
        float lz = __shfl_up(zz.w, 1);
        float lp = __shfl_up(zp.w, 1);
        float rm = __shfl_down(zm.x, 1);
        float rz = __shfl_down(zz.x, 1);
        float rp = __shfl_down(zp.x, 1);
        if (lane == 0)  { lm = 0.f; lz = 0.f; lp = 0.f; }
        if (lane == 63) { rm = 0.f; rz = 0.f; rp = 0.f; }

        // 6-wide windows: indices 0..5 cover w-1 .. w+4
        float m6[6] = { lm, zm.x, zm.y, zm.z, zm.w, rm };
        float z6[6] = { lz, zz.x, zz.y, zz.z, zz.w, rz };
        float p6[6] = { lp, zp.x, zp.y, zp.z, zp.w, rp };
        float sqm[6], sqz[6], sqp[6];
#pragma unroll
        for (int i = 0; i < 6; ++i) {
            sqm[i] = m6[i] * m6[i];
            sqz[i] = z6[i] * z6[i];
            sqp[i] = p6[i] * p6[i];
        }
        // norm-sum accumulation (reuse squares; own w positions = window 1..4)
#pragma unroll
        for (int x = 0; x < 4; ++x) {
            si[0][x] += sqm[x + 1];
            si[1][x] += sqz[x + 1];
            si[2][x] += sqp[x + 1];
        }
        se[0] = fmaf(ee.x, ee.x, se[0]);
        se[1] = fmaf(ee.y, ee.y, se[1]);
        se[2] = fmaf(ee.z, ee.z, se[2]);
        se[3] = fmaf(ee.w, ee.w, se[3]);

        float pe[4] = { z6[1] * ee.x, z6[2] * ee.y, z6[3] * ee.z, z6[4] * ee.w };
#pragma unroll
        for (int x = 0; x < 4; ++x) {
            acc[0][x] = fmaf(sqm[x],     pe[x], acc[0][x]);  // (-1,-1)
            acc[1][x] = fmaf(sqm[x + 1], pe[x], acc[1][x]);  // (-1, 0)
            acc[2][x] = fmaf(sqm[x + 2], pe[x], acc[2][x]);  // (-1,+1)
            acc[3][x] = fmaf(sqz[x],     pe[x], acc[3][x]);  // ( 0,-1)
            acc[4][x] = fmaf(sqz[x + 2], pe[x], acc[4][x]);  // ( 0,+1)
            acc[5][x] = fmaf(sqp[x],     pe[x], acc[5][x]);  // (+1,-1)
            acc[6][x] = fmaf(sqp[x + 1], pe[x], acc[6][x]);  // (+1, 0)
            acc[7][x] = fmaf(sqp[x + 2], pe[x], acc[7][x]);  // (+1,+1)
        }
    }

    // ---- cross-wave tree reduction through LDS (48 floats per lane) ----
    // value index v: 0..31 = acc[v>>2][v&3], 32..43 = si[(v-32)>>2][(v-32)&3],
    // 44..47 = se[v-44]. Layout [value][lane]: stride-1 across lanes.
    if (wv >= 2) {
        const int s = wv - 2;
#pragma unroll
        for (int k = 0; k < 8; ++k)
#pragma unroll
            for (int x = 0; x < 4; ++x) red[s][k * 4 + x][lane] = acc[k][x];
#pragma unroll
        for (int r = 0; r < 3; ++r)
#pragma unroll
            for (int x = 0; x < 4; ++x) red[s][32 + r * 4 + x][lane] = si[r][x];
#pragma unroll
        for (int x = 0; x < 4; ++x) red[s][44 + x][lane] = se[x];
    }
    __syncthreads();
    if (wv < 2) {
        const int s = wv;
#pragma unroll
        for (int k = 0; k < 8; ++k)
#pragma unroll
            for (int x = 0; x < 4; ++x) acc[k][x] += red[s][k * 4 + x][lane];
#pragma unroll
        for (int r = 0; r < 3; ++r)
#pragma unroll
            for (int x = 0; x < 4; ++x) si[r][x] += red[s][32 + r * 4 + x][lane];
#pragma unroll
        for (int x = 0; x < 4; ++x) se[x] += red[s][44 + x][lane];
    }
    __syncthreads();
    if (wv == 1) {
#pragma unroll
        for (int k = 0; k < 8; ++k)
#pragma unroll
            for (int x = 0; x < 4; ++x) red[0][k * 4 + x][lane] = acc[k][x];
#pragma unroll
        for (int r = 0; r < 3; ++r)
#pragma unroll
            for (int x = 0; x < 4; ++x) red[0][32 + r * 4 + x][lane] = si[r][x];
#pragma unroll
        for (int x = 0; x < 4; ++x) red[0][44 + x][lane] = se[x];
    }
    __syncthreads();
    if (wv != 0) return;

#pragma unroll
    for (int k = 0; k < 8; ++k)
#pragma unroll
        for (int x = 0; x < 4; ++x) acc[k][x] += red[0][k * 4 + x][lane];
#pragma unroll
    for (int r = 0; r < 3; ++r)
#pragma unroll
        for (int x = 0; x < 4; ++x) si[r][x] += red[0][32 + r * 4 + x][lane];
#pragma unroll
    for (int x = 0; x < 4; ++x) se[x] += red[0][44 + x][lane];

    // ---- epilogue (wave 0 only): reciprocal norms, windows, scale, relu ----
    float rnm[4], rnz[4], rnp[4], rne[4];
#pragma unroll
    for (int x = 0; x < 4; ++x) {
        rnm[x] = 1.f / fmaxf(sqrtf(si[0][x]), 1e-12f);
        rnz[x] = 1.f / fmaxf(sqrtf(si[1][x]), 1e-12f);
        rnp[x] = 1.f / fmaxf(sqrtf(si[2][x]), 1e-12f);
        rne[x] = 1.f / fmaxf(sqrtf(se[x]), 1e-12f);
    }

    float lnm = __shfl_up(rnm[3], 1);
    float lnz = __shfl_up(rnz[3], 1);
    float lnp = __shfl_up(rnp[3], 1);
    float rnm_ = __shfl_down(rnm[0], 1);
    float rnz_ = __shfl_down(rnz[0], 1);
    float rnp_ = __shfl_down(rnp[0], 1);
    if (lane == 0)  { lnm = 0.f; lnz = 0.f; lnp = 0.f; }
    if (lane == 63) { rnm_ = 0.f; rnz_ = 0.f; rnp_ = 0.f; }

    float nm6[6] = { lnm, rnm[0], rnm[1], rnm[2], rnm[3], rnm_ };
    float nz6[6] = { lnz, rnz[0], rnz[1], rnz[2], rnz[3], rnz_ };
    float np6[6] = { lnp, rnp[0], rnp[1], rnp[2], rnp[3], rnp_ };

    float ctr[4];
#pragma unroll
    for (int x = 0; x < 4; ++x) ctr[x] = nz6[x + 1] * rne[x];

    float* outp = out + (((size_t)b * 8) * NH + h) * NW + w;
#pragma unroll
    for (int k = 0; k < 8; ++k) {
        float nbv[4];
#pragma unroll
        for (int x = 0; x < 4; ++x) {
            float v;
            switch (k) {
                case 0: v = nm6[x];     break;
                case 1: v = nm6[x + 1]; break;
                case 2: v = nm6[x + 2]; break;
                case 3: v = nz6[x];     break;
                case 4: v = nz6[x + 2]; break;
                case 5: v = np6[x];     break;
                case 6: v = np6[x + 1]; break;
                default: v = np6[x + 2]; break;
            }
            nbv[x] = v;
        }
        float4 o;
        o.x = fmaxf(acc[k][0] * (nbv[0] * nbv[0]) * ctr[0], 0.f);
        o.y = fmaxf(acc[k][1] * (nbv[1] * nbv[1]) * ctr[1], 0.f);
        o.z = fmaxf(acc[k][2] * (nbv[2] * nbv[2]) * ctr[2], 0.f);
        o.w = fmaxf(acc[k][3] * (nbv[3] * nbv[3]) * ctr[3], 0.f);
        *(float4*)(outp + (size_t)k * NH * NW) = o;
    }
}

extern "C" void kernel_launch(void* const* d_in, const int* in_sizes, int n_in,
                              void* d_out, int out_size, void* d_ws, size_t ws_size,
                              hipStream_t stream) {
    (void)in_sizes; (void)n_in; (void)out_size; (void)d_ws; (void)ws_size;
    const float* img = (const float*)d_in[0];
    const float* ev  = (const float*)d_in[1];
    float* out = (float*)d_out;

    // 1024 blocks (one per row), 256 threads (4 waves x 16 channels)
    k_fused<<<NB * NH, 256, 0, stream>>>(img, ev, out);
}